// Round 1
// baseline (1228.701 us; speedup 1.0000x reference)
//
#include <hip/hip_runtime.h>

// Problem constants (B=4, T=512, S=512, D=1024, V=32000, E=512)
#define BT    2048          // B*T rows
#define DD    1024
#define SS    512
#define VV    32000
#define EE    512
#define OUTW  32512         // V+E

typedef __bf16 bf16x8 __attribute__((ext_vector_type(8)));
typedef float  f32x4  __attribute__((ext_vector_type(4)));

static __device__ __forceinline__ unsigned short f2bf(float f) {
    unsigned int u = __builtin_bit_cast(unsigned int, f);
    u += 0x7FFFu + ((u >> 16) & 1u);      // round-to-nearest-even
    return (unsigned short)(u >> 16);
}

// ---------------------------------------------------------------- K1: src_idx
// Recover argmax of one-hot src_map rows. 1 wave per (b,s) row.
__global__ void k_srcidx(const float* __restrict__ smap, int* __restrict__ sidx) {
    int lane = threadIdx.x & 63, wid = threadIdx.x >> 6;
    int r = blockIdx.x * 4 + wid;                 // r < 2048
    const float* row = smap + (size_t)r * EE;
    int found = 0;
#pragma unroll
    for (int i = 0; i < 8; ++i) {
        int e = lane + 64 * i;
        if (row[e] > 0.5f) found = e;
    }
    for (int off = 32; off; off >>= 1) found = max(found, __shfl_xor(found, off));
    if (lane == 0) sidx[r] = found;
}

// ---------------------------------------------------------------- K2: p_copy
__global__ void k_pcopy(const float* __restrict__ q, const float* __restrict__ Wc,
                        const float* __restrict__ bc, float* __restrict__ pc) {
    int lane = threadIdx.x & 63, wid = threadIdx.x >> 6;
    int r = blockIdx.x * 4 + wid;
    const float* row = q + (size_t)r * DD;
    float s = 0.f;
#pragma unroll
    for (int i = 0; i < 16; ++i) { int d = lane + 64 * i; s += row[d] * Wc[d]; }
    for (int off = 32; off; off >>= 1) s += __shfl_xor(s, off);
    if (lane == 0) pc[r] = 1.0f / (1.0f + __expf(-(s + bc[0])));
}

// ------------------------------------------------- K3: fp32 GEMM (64x64 tile)
// C[M,N] = A[M,K] * B[K,N]  (TRANSB=0)   or  A[M,K] * B[N,K]^T  (TRANSB=1)
// grid: x = N/64, y = M/64, z = batch
template <int TRANSB>
__global__ __launch_bounds__(256) void k_gemm_f32(
        const float* __restrict__ A, int lda, long long sA,
        const float* __restrict__ B, int ldb, long long sB,
        float* __restrict__ C, int ldc, long long sC, int K) {
    __shared__ __align__(16) float As[32][68];   // [k][m], padded
    __shared__ __align__(16) float Bs[32][68];   // [k][n], padded
    int tid = threadIdx.x;
    int tx = tid & 15, ty = tid >> 4;
    int n0 = blockIdx.x * 64, m0 = blockIdx.y * 64;
    A += (long long)blockIdx.z * sA;
    B += (long long)blockIdx.z * sB;
    C += (long long)blockIdx.z * sC;
    float acc[4][4] = {};
    for (int k0 = 0; k0 < K; k0 += 32) {
        // stage A (64 rows x 32 k) transposed -> As[k][m]
#pragma unroll
        for (int i = 0; i < 2; ++i) {
            int f = tid + 256 * i;
            int m = f >> 3, kq = f & 7;
            float4 v = *(const float4*)&A[(size_t)(m0 + m) * lda + k0 + kq * 4];
            As[kq * 4 + 0][m] = v.x; As[kq * 4 + 1][m] = v.y;
            As[kq * 4 + 2][m] = v.z; As[kq * 4 + 3][m] = v.w;
        }
        if (TRANSB) {   // B rows are n, k contiguous -> transpose into Bs[k][n]
#pragma unroll
            for (int i = 0; i < 2; ++i) {
                int f = tid + 256 * i;
                int n = f >> 3, kq = f & 7;
                float4 v = *(const float4*)&B[(size_t)(n0 + n) * ldb + k0 + kq * 4];
                Bs[kq * 4 + 0][n] = v.x; Bs[kq * 4 + 1][n] = v.y;
                Bs[kq * 4 + 2][n] = v.z; Bs[kq * 4 + 3][n] = v.w;
            }
        } else {        // B rows are k, n contiguous -> direct Bs[k][n]
#pragma unroll
            for (int i = 0; i < 2; ++i) {
                int f = tid + 256 * i;
                int k = f >> 4, nq = f & 15;
                float4 v = *(const float4*)&B[(size_t)(k0 + k) * ldb + n0 + nq * 4];
                *(float4*)&Bs[k][nq * 4] = v;
            }
        }
        __syncthreads();
#pragma unroll
        for (int k = 0; k < 32; ++k) {
            float4 av = *(const float4*)&As[k][ty * 4];
            float4 bv = *(const float4*)&Bs[k][tx * 4];
            float a4[4] = {av.x, av.y, av.z, av.w};
            float b4[4] = {bv.x, bv.y, bv.z, bv.w};
#pragma unroll
            for (int i = 0; i < 4; ++i)
#pragma unroll
                for (int j = 0; j < 4; ++j) acc[i][j] += a4[i] * b4[j];
        }
        __syncthreads();
    }
#pragma unroll
    for (int i = 0; i < 4; ++i) {
        float4 o = {acc[i][0], acc[i][1], acc[i][2], acc[i][3]};
        *(float4*)&C[(size_t)(m0 + ty * 4 + i) * ldc + n0 + tx * 4] = o;
    }
}

// ------------------------------- K4: masked copy-softmax + scatter (per row)
__global__ __launch_bounds__(256) void k_copy_softmax(
        const float* __restrict__ attn, const int* __restrict__ mask,
        const float* __restrict__ pc, const int* __restrict__ sidx,
        float* __restrict__ out) {
    __shared__ float sacc[EE];
    __shared__ float red[8];
    int tid = threadIdx.x;
    int r = blockIdx.x;             // 0..2047
    int b = r >> 9;
    const float* arow = attn + (size_t)r * SS;
    const int*   mrow = mask + (size_t)b * SS;
    const int*   irow = sidx + (size_t)b * SS;
    float a0 = arow[tid], a1 = arow[tid + 256];
    if (mrow[tid])       a0 = -1e18f;
    if (mrow[tid + 256]) a1 = -1e18f;
    sacc[tid] = 0.f; sacc[tid + 256] = 0.f;
    int lane = tid & 63, wid = tid >> 6;
    // block max
    float m = fmaxf(a0, a1);
    for (int off = 32; off; off >>= 1) m = fmaxf(m, __shfl_xor(m, off));
    if (lane == 0) red[wid] = m;
    __syncthreads();
    m = fmaxf(fmaxf(red[0], red[1]), fmaxf(red[2], red[3]));
    // block sum of exp
    float e0 = __expf(a0 - m), e1 = __expf(a1 - m);
    float z = e0 + e1;
    for (int off = 32; off; off >>= 1) z += __shfl_xor(z, off);
    if (lane == 0) red[4 + wid] = z;
    __syncthreads();
    z = red[4] + red[5] + red[6] + red[7];
    float scale = pc[r] / z;
    atomicAdd(&sacc[irow[tid]],       e0 * scale);
    atomicAdd(&sacc[irow[tid + 256]], e1 * scale);
    __syncthreads();
    float* orow = out + (size_t)r * OUTW + VV;
    orow[tid] = sacc[tid];
    orow[tid + 256] = sacc[tid + 256];
}

// -------------------- K5: gen logits GEMM, bf16 MFMA, 128x128 tile, BK=32
// C[2048,32000] = Q[2048,1024] * W[1024,32000]; logits written into out rows.
__global__ __launch_bounds__(256) void k_gen_logits(
        const float* __restrict__ Q, const float* __restrict__ W,
        float* __restrict__ out) {
    __shared__ __align__(16) unsigned short As[128 * 40];  // [m][k] bf16, pad 40
    __shared__ __align__(16) unsigned short Bs[128 * 40];  // [n][k] bf16, pad 40
    int tid = threadIdx.x;
    int lane = tid & 63, wid = tid >> 6;
    int m0 = blockIdx.x * 128;       // 16 row tiles (fast dim -> W-panel L2 reuse)
    int n0 = blockIdx.y * 128;       // 250 col tiles
    int wrow = (wid >> 1) * 64, wcol = (wid & 1) * 64;
    f32x4 zero = {0.f, 0.f, 0.f, 0.f};
    f32x4 acc[4][4];
#pragma unroll
    for (int i = 0; i < 4; ++i)
#pragma unroll
        for (int j = 0; j < 4; ++j) acc[i][j] = zero;

    for (int k0 = 0; k0 < DD; k0 += 32) {
        // stage A: Q[m0..+128][k0..+32] f32 -> bf16 As[m][k]
#pragma unroll
        for (int i = 0; i < 4; ++i) {
            int f = tid + 256 * i;
            int m = f >> 3, kq = f & 7;
            float4 v = *(const float4*)&Q[(size_t)(m0 + m) * DD + k0 + kq * 4];
            ushort4 pk = make_ushort4(f2bf(v.x), f2bf(v.y), f2bf(v.z), f2bf(v.w));
            *(ushort4*)&As[m * 40 + kq * 4] = pk;
        }
        // stage B: W[k0..+32][n0..+128] f32 -> bf16 Bs[n][k] (transposed)
#pragma unroll
        for (int i = 0; i < 4; ++i) {
            int f = tid + 256 * i;
            int k = f >> 5, nq = f & 31;
            float4 v = *(const float4*)&W[(size_t)(k0 + k) * VV + n0 + nq * 4];
            Bs[(nq * 4 + 0) * 40 + k] = f2bf(v.x);
            Bs[(nq * 4 + 1) * 40 + k] = f2bf(v.y);
            Bs[(nq * 4 + 2) * 40 + k] = f2bf(v.z);
            Bs[(nq * 4 + 3) * 40 + k] = f2bf(v.w);
        }
        __syncthreads();
        int kb = (lane >> 4) * 8;
        bf16x8 af[4], bfv[4];
#pragma unroll
        for (int mi = 0; mi < 4; ++mi)
            af[mi] = *(const bf16x8*)&As[(wrow + mi * 16 + (lane & 15)) * 40 + kb];
#pragma unroll
        for (int ni = 0; ni < 4; ++ni)
            bfv[ni] = *(const bf16x8*)&Bs[(wcol + ni * 16 + (lane & 15)) * 40 + kb];
#pragma unroll
        for (int mi = 0; mi < 4; ++mi)
#pragma unroll
            for (int ni = 0; ni < 4; ++ni)
                acc[mi][ni] = __builtin_amdgcn_mfma_f32_16x16x32_bf16(
                    af[mi], bfv[ni], acc[mi][ni], 0, 0, 0);
        __syncthreads();
    }
    // epilogue: C/D layout col=lane&15, row=(lane>>4)*4+reg  [verified m89]
    int rq = (lane >> 4) * 4, cq = lane & 15;
#pragma unroll
    for (int mi = 0; mi < 4; ++mi)
#pragma unroll
        for (int ni = 0; ni < 4; ++ni)
#pragma unroll
            for (int j = 0; j < 4; ++j) {
                int row = m0 + wrow + mi * 16 + rq + j;
                int col = n0 + wcol + ni * 16 + cq;
                out[(size_t)row * OUTW + col] = acc[mi][ni][j];
            }
}

// ------------------- K6: gen softmax over V=32000 (in place on out rows)
__global__ __launch_bounds__(256) void k_gen_softmax(
        float* __restrict__ out, const float* __restrict__ bg,
        const float* __restrict__ pc) {
    __shared__ float redm[4], redz[4];
    int tid = threadIdx.x;
    int r = blockIdx.x;
    float* row = out + (size_t)r * OUTW;
    float m = -3.4e38f, z = 0.f;
    for (int v = tid; v < VV; v += 256) {
        float l = (v == 0) ? -1e-20f : row[v] + bg[v];
        float mn = fmaxf(m, l);
        z = z * __expf(m - mn) + __expf(l - mn);
        m = mn;
    }
    for (int off = 32; off; off >>= 1) {
        float m2 = __shfl_xor(m, off), z2 = __shfl_xor(z, off);
        float mn = fmaxf(m, m2);
        z = z * __expf(m - mn) + z2 * __expf(m2 - mn);
        m = mn;
    }
    int lane = tid & 63, wid = tid >> 6;
    if (lane == 0) { redm[wid] = m; redz[wid] = z; }
    __syncthreads();
    m = redm[0]; z = redz[0];
#pragma unroll
    for (int w = 1; w < 4; ++w) {
        float m2 = redm[w], z2 = redz[w];
        float mn = fmaxf(m, m2);
        z = z * __expf(m - mn) + z2 * __expf(m2 - mn);
        m = mn;
    }
    float scale = (1.0f - pc[r]) / z;
    for (int v = tid; v < VV; v += 256) {
        float l = (v == 0) ? -1e-20f : row[v] + bg[v];
        row[v] = __expf(l - m) * scale;
    }
}

// ---------------------------------------------------------------- launcher
extern "C" void kernel_launch(void* const* d_in, const int* in_sizes, int n_in,
                              void* d_out, int out_size, void* d_ws, size_t ws_size,
                              hipStream_t stream) {
    (void)in_sizes; (void)n_in; (void)out_size; (void)ws_size;
    const float* query = (const float*)d_in[0];
    const float* mem   = (const float*)d_in[1];
    const int*   mask  = (const int*)d_in[2];     // bool -> int32 per harness
    const float* smap  = (const float*)d_in[3];
    const float* Win   = (const float*)d_in[4];
    const float* Wc    = (const float*)d_in[5];
    const float* bc    = (const float*)d_in[6];
    const float* Wg    = (const float*)d_in[7];
    const float* bg    = (const float*)d_in[8];
    float* out = (float*)d_out;

    // workspace layout (~12.6 MB)
    float* QW   = (float*)d_ws;                      // 2048*1024
    float* attn = QW + (size_t)BT * DD;              // 4*512*512
    float* pc   = attn + (size_t)4 * SS * SS;        // 2048
    int*   sidx = (int*)(pc + BT);                   // 2048

    k_srcidx<<<512, 256, 0, stream>>>(smap, sidx);
    k_pcopy <<<512, 256, 0, stream>>>(query, Wc, bc, pc);

    // QW = query @ W_in   (NN, M=2048 N=1024 K=1024)
    k_gemm_f32<0><<<dim3(16, 32, 1), 256, 0, stream>>>(
        query, DD, 0LL, Win, DD, 0LL, QW, DD, 0LL, DD);
    // attn[b] = QW[b] @ mem[b]^T   (NT, M=512 N=512 K=1024, batch=4)
    k_gemm_f32<1><<<dim3(8, 8, 4), 256, 0, stream>>>(
        QW, DD, (long long)SS * DD, mem, DD, (long long)SS * DD,
        attn, SS, (long long)SS * SS, DD);

    // gen logits into out's first V columns
    k_gen_logits<<<dim3(16, 250), 256, 0, stream>>>(query, Wg, out);

    // copy path: masked softmax + scatter into out's last E columns
    k_copy_softmax<<<BT, 256, 0, stream>>>(attn, mask, pc, sidx, out);

    // gen softmax (in place) with (1 - p_copy) scaling
    k_gen_softmax<<<BT, 256, 0, stream>>>(out, bg, pc);
}

// Round 5
// 822.457 us; speedup vs baseline: 1.4939x; 1.4939x over previous
//
#include <hip/hip_runtime.h>

// Problem constants (B=4, T=512, S=512, D=1024, V=32000, E=512)
#define BT    2048
#define DD    1024
#define SS    512
#define VV    32000
#define EE    512
#define OUTW  32512

typedef __bf16 bf16x8 __attribute__((ext_vector_type(8)));
typedef float  f32x4  __attribute__((ext_vector_type(4)));
typedef unsigned short u16x8 __attribute__((ext_vector_type(8)));

static __device__ __forceinline__ unsigned short f2bf(float f) {
    unsigned int u = __builtin_bit_cast(unsigned int, f);
    u += 0x7FFFu + ((u >> 16) & 1u);
    return (unsigned short)(u >> 16);
}

typedef __attribute__((address_space(1))) const unsigned int gu32;
typedef __attribute__((address_space(3))) unsigned int lu32;
static __device__ __forceinline__ void gload16(const void* g, void* l) {
    __builtin_amdgcn_global_load_lds((gu32*)g, (lu32*)l, 16, 0, 0);
}

// ---------------------------------------------------------------- K1: src_idx
__global__ void k_srcidx(const float* __restrict__ smap, int* __restrict__ sidx) {
    int lane = threadIdx.x & 63, wid = threadIdx.x >> 6;
    int r = blockIdx.x * 4 + wid;
    const float* row = smap + (size_t)r * EE;
    int found = 0;
#pragma unroll
    for (int i = 0; i < 8; ++i) {
        int e = lane + 64 * i;
        if (row[e] > 0.5f) found = e;
    }
    for (int off = 32; off; off >>= 1) found = max(found, __shfl_xor(found, off));
    if (lane == 0) sidx[r] = found;
}

// ---------------------------------------------------------------- K2: p_copy
__global__ void k_pcopy(const float* __restrict__ q, const float* __restrict__ Wc,
                        const float* __restrict__ bc, float* __restrict__ pc) {
    int lane = threadIdx.x & 63, wid = threadIdx.x >> 6;
    int r = blockIdx.x * 4 + wid;
    const float* row = q + (size_t)r * DD;
    float s = 0.f;
#pragma unroll
    for (int i = 0; i < 16; ++i) { int d = lane + 64 * i; s += row[d] * Wc[d]; }
    for (int off = 32; off; off >>= 1) s += __shfl_xor(s, off);
    if (lane == 0) pc[r] = 1.0f / (1.0f + __expf(-(s + bc[0])));
}

// ------------------------------------------------- K3: fp32 GEMM (64x64 tile)
template <int TRANSB>
__global__ __launch_bounds__(256) void k_gemm_f32(
        const float* __restrict__ A, int lda, long long sA,
        const float* __restrict__ B, int ldb, long long sB,
        float* __restrict__ C, int ldc, long long sC, int K) {
    __shared__ __align__(16) float As[32][68];
    __shared__ __align__(16) float Bs[32][68];
    int tid = threadIdx.x;
    int tx = tid & 15, ty = tid >> 4;
    int n0 = blockIdx.x * 64, m0 = blockIdx.y * 64;
    A += (long long)blockIdx.z * sA;
    B += (long long)blockIdx.z * sB;
    C += (long long)blockIdx.z * sC;
    float acc[4][4] = {};
    for (int k0 = 0; k0 < K; k0 += 32) {
#pragma unroll
        for (int i = 0; i < 2; ++i) {
            int f = tid + 256 * i;
            int m = f >> 3, kq = f & 7;
            float4 v = *(const float4*)&A[(size_t)(m0 + m) * lda + k0 + kq * 4];
            As[kq * 4 + 0][m] = v.x; As[kq * 4 + 1][m] = v.y;
            As[kq * 4 + 2][m] = v.z; As[kq * 4 + 3][m] = v.w;
        }
        if (TRANSB) {
#pragma unroll
            for (int i = 0; i < 2; ++i) {
                int f = tid + 256 * i;
                int n = f >> 3, kq = f & 7;
                float4 v = *(const float4*)&B[(size_t)(n0 + n) * ldb + k0 + kq * 4];
                Bs[kq * 4 + 0][n] = v.x; Bs[kq * 4 + 1][n] = v.y;
                Bs[kq * 4 + 2][n] = v.z; Bs[kq * 4 + 3][n] = v.w;
            }
        } else {
#pragma unroll
            for (int i = 0; i < 2; ++i) {
                int f = tid + 256 * i;
                int k = f >> 4, nq = f & 15;
                float4 v = *(const float4*)&B[(size_t)(k0 + k) * ldb + n0 + nq * 4];
                *(float4*)&Bs[k][nq * 4] = v;
            }
        }
        __syncthreads();
#pragma unroll
        for (int k = 0; k < 32; ++k) {
            float4 av = *(const float4*)&As[k][ty * 4];
            float4 bv = *(const float4*)&Bs[k][tx * 4];
            float a4[4] = {av.x, av.y, av.z, av.w};
            float b4[4] = {bv.x, bv.y, bv.z, bv.w};
#pragma unroll
            for (int i = 0; i < 4; ++i)
#pragma unroll
                for (int j = 0; j < 4; ++j) acc[i][j] += a4[i] * b4[j];
        }
        __syncthreads();
    }
#pragma unroll
    for (int i = 0; i < 4; ++i) {
        float4 o = {acc[i][0], acc[i][1], acc[i][2], acc[i][3]};
        *(float4*)&C[(size_t)(m0 + ty * 4 + i) * ldc + n0 + tx * 4] = o;
    }
}

// ------------------------------- K4: masked copy-softmax + scatter (per row)
__global__ __launch_bounds__(256) void k_copy_softmax(
        const float* __restrict__ attn, const int* __restrict__ mask,
        const float* __restrict__ pc, const int* __restrict__ sidx,
        float* __restrict__ out) {
    __shared__ float sacc[EE];
    __shared__ float red[8];
    int tid = threadIdx.x;
    int r = blockIdx.x;
    int b = r >> 9;
    const float* arow = attn + (size_t)r * SS;
    const int*   mrow = mask + (size_t)b * SS;
    const int*   irow = sidx + (size_t)b * SS;
    float a0 = arow[tid], a1 = arow[tid + 256];
    if (mrow[tid])       a0 = -1e18f;
    if (mrow[tid + 256]) a1 = -1e18f;
    sacc[tid] = 0.f; sacc[tid + 256] = 0.f;
    int lane = tid & 63, wid = tid >> 6;
    float m = fmaxf(a0, a1);
    for (int off = 32; off; off >>= 1) m = fmaxf(m, __shfl_xor(m, off));
    if (lane == 0) red[wid] = m;
    __syncthreads();
    m = fmaxf(fmaxf(red[0], red[1]), fmaxf(red[2], red[3]));
    float e0 = __expf(a0 - m), e1 = __expf(a1 - m);
    float z = e0 + e1;
    for (int off = 32; off; off >>= 1) z += __shfl_xor(z, off);
    if (lane == 0) red[4 + wid] = z;
    __syncthreads();
    z = red[4] + red[5] + red[6] + red[7];
    float scale = pc[r] / z;
    atomicAdd(&sacc[irow[tid]],       e0 * scale);
    atomicAdd(&sacc[irow[tid + 256]], e1 * scale);
    __syncthreads();
    float* orow = out + (size_t)r * OUTW + VV;
    orow[tid] = sacc[tid];
    orow[tid + 256] = sacc[tid + 256];
}

// ------------------------------------------ K5a: Q f32 -> bf16 (no transpose)
__global__ __launch_bounds__(256) void k_convert_q(
        const float* __restrict__ Q, unsigned short* __restrict__ Qb) {
    int idx = blockIdx.x * 256 + threadIdx.x;     // 2048*1024/4 = 524288
    float4 v = *(const float4*)&Q[(size_t)idx * 4];
    ushort4 pk = make_ushort4(f2bf(v.x), f2bf(v.y), f2bf(v.z), f2bf(v.w));
    *(ushort4*)&Qb[(size_t)idx * 4] = pk;
}

// -------------------- K5b: W_gen f32[k][n] -> bf16 Wt[n_local][k] (64x64 tile)
__global__ __launch_bounds__(256) void k_transpose_w(
        const float* __restrict__ W, unsigned short* __restrict__ Wt, int nbase) {
    __shared__ unsigned short Ls[64 * 65];
    int tid = threadIdx.x;
    int nloc0 = blockIdx.x * 64;            // local n offset within chunk
    int n0g = nbase + nloc0;                // global n
    int k0 = blockIdx.y * 64;
#pragma unroll
    for (int i = 0; i < 4; ++i) {
        int kl = (tid >> 4) + i * 16;
        int n4 = (tid & 15) * 4;
        float4 v = *(const float4*)&W[(size_t)(k0 + kl) * VV + n0g + n4];
        Ls[(n4 + 0) * 65 + kl] = f2bf(v.x);
        Ls[(n4 + 1) * 65 + kl] = f2bf(v.y);
        Ls[(n4 + 2) * 65 + kl] = f2bf(v.z);
        Ls[(n4 + 3) * 65 + kl] = f2bf(v.w);
    }
    __syncthreads();
#pragma unroll
    for (int j = 0; j < 2; ++j) {
        int nl = (tid >> 3) + j * 32;
        int kc = (tid & 7) * 8;
        u16x8 p;
#pragma unroll
        for (int e = 0; e < 8; ++e) p[e] = Ls[nl * 65 + kc + e];
        *(u16x8*)&Wt[(size_t)(nloc0 + nl) * DD + k0 + kc] = p;
    }
}

// -------------- K6: gen logits GEMM bf16 MFMA, 128x128 tile BK=64, m97-style
// + fused bias/PAD + per-block softmax partials (row max, sumexp) -> pm/pz
__global__ __launch_bounds__(256) void k_gen_logits(
        const unsigned short* __restrict__ Qb, const unsigned short* __restrict__ Wt,
        int pbase, const float* __restrict__ bg, float* __restrict__ out,
        float* __restrict__ pm, float* __restrict__ pz) {
    __shared__ __align__(16) unsigned short As[128 * 64];   // 16 KB, linear+swz
    __shared__ __align__(16) unsigned short Bs[128 * 64];
    int tid = threadIdx.x;
    int lane = tid & 63, wid = tid >> 6;
    // bijective XCD swizzle (nwg = 16*np, always %8==0), m-fast within XCD chunk
    int nwg = gridDim.x;
    int id = blockIdx.x;
    int wg = (id & 7) * (nwg >> 3) + (id >> 3);
    int m0 = (wg & 15) * 128;
    int pl = wg >> 4;                 // local panel in this chunk
    int panel = pbase + pl;
    int n0g = panel * 128;
    int wrow = (wid >> 1) * 64, wcol = (wid & 1) * 64;
    int wbase = tid & 192;

    f32x4 zero = {0.f, 0.f, 0.f, 0.f};
    f32x4 acc[4][4];
#pragma unroll
    for (int i = 0; i < 4; ++i)
#pragma unroll
        for (int j = 0; j < 4; ++j) acc[i][j] = zero;

    const unsigned short* Ag = Qb + (size_t)m0 * DD;
    const unsigned short* Bg = Wt + (size_t)pl * 128 * DD;
    int lr = lane & 15, lh = lane >> 4;

    for (int k0 = 0; k0 < DD; k0 += 64) {
        // stage: linear LDS dest, XOR-swizzled global source (rule #21)
#pragma unroll
        for (int i = 0; i < 4; ++i) {
            int s = i * 256 + tid;
            int row = s >> 3, sl = s & 7;
            int slp = sl ^ (row & 7);
            void* ldsA = (void*)&As[(size_t)(i * 256 + wbase) * 8];
            void* ldsB = (void*)&Bs[(size_t)(i * 256 + wbase) * 8];
            gload16(Ag + (size_t)row * DD + k0 + slp * 8, ldsA);
            gload16(Bg + (size_t)row * DD + k0 + slp * 8, ldsB);
        }
        __syncthreads();
#pragma unroll
        for (int ks = 0; ks < 2; ++ks) {
            int g = ks * 4 + lh;          // global 16B k-slot within tile
            bf16x8 af[4], bfv[4];
#pragma unroll
            for (int mi = 0; mi < 4; ++mi) {
                int row = wrow + mi * 16 + lr;
                af[mi] = *(const bf16x8*)&As[row * 64 + (g ^ (row & 7)) * 8];
            }
#pragma unroll
            for (int ni = 0; ni < 4; ++ni) {
                int row = wcol + ni * 16 + lr;
                bfv[ni] = *(const bf16x8*)&Bs[row * 64 + (g ^ (row & 7)) * 8];
            }
#pragma unroll
            for (int mi = 0; mi < 4; ++mi)
#pragma unroll
                for (int ni = 0; ni < 4; ++ni)
                    acc[mi][ni] = __builtin_amdgcn_mfma_f32_16x16x32_bf16(
                        af[mi], bfv[ni], acc[mi][ni], 0, 0, 0);
        }
        __syncthreads();
    }
    // epilogue: bias + PAD + store + per-row partial (max, sumexp) over 128 cols
    int colb = n0g + wcol + lr;
    float bias[4];
#pragma unroll
    for (int ni = 0; ni < 4; ++ni) bias[ni] = bg[colb + ni * 16];
    float* sm_ = (float*)As;          // 256 floats
    float* sz_ = sm_ + 256;
#pragma unroll
    for (int mi = 0; mi < 4; ++mi) {
#pragma unroll
        for (int j = 0; j < 4; ++j) {
            int row = m0 + wrow + mi * 16 + lh * 4 + j;
            float v[4];
#pragma unroll
            for (int ni = 0; ni < 4; ++ni) {
                float x = acc[mi][ni][j] + bias[ni];
                if (colb + ni * 16 == 0) x = -1e-20f;
                v[ni] = x;
                out[(size_t)row * OUTW + colb + ni * 16] = x;
            }
            float mx = fmaxf(fmaxf(v[0], v[1]), fmaxf(v[2], v[3]));
            float sm = __expf(v[0] - mx) + __expf(v[1] - mx) +
                       __expf(v[2] - mx) + __expf(v[3] - mx);
#pragma unroll
            for (int o = 1; o < 16; o <<= 1) {
                float m2 = __shfl_xor(mx, o), s2 = __shfl_xor(sm, o);
                float mn = fmaxf(mx, m2);
                sm = sm * __expf(mx - mn) + s2 * __expf(m2 - mn);
                mx = mn;
            }
            if (lr == 0) {
                int rl = wrow + mi * 16 + lh * 4 + j;
                sm_[rl * 2 + (wid & 1)] = mx;
                sz_[rl * 2 + (wid & 1)] = sm;
            }
        }
    }
    __syncthreads();
    if (tid < 128) {
        float ma = sm_[tid * 2], mb = sm_[tid * 2 + 1];
        float za = sz_[tid * 2], zb = sz_[tid * 2 + 1];
        float mn = fmaxf(ma, mb);
        float zz = za * __expf(ma - mn) + zb * __expf(mb - mn);
        pm[(size_t)(m0 + tid) * 256 + panel] = mn;
        pz[(size_t)(m0 + tid) * 256 + panel] = zz;
    }
}

// ------------------- K7: gen softmax finalize (merge partials, 1 rw pass)
__global__ __launch_bounds__(256) void k_gen_softmax(
        float* __restrict__ out, const float* __restrict__ pm,
        const float* __restrict__ pz, const float* __restrict__ pc) {
    __shared__ float rm[4], rz[4];
    int tid = threadIdx.x, r = blockIdx.x;
    int lane = tid & 63, wid = tid >> 6;
    float m = -3.0e38f, z = 0.f;
    if (tid < 250) { m = pm[(size_t)r * 256 + tid]; z = pz[(size_t)r * 256 + tid]; }
    for (int o = 32; o; o >>= 1) {
        float m2 = __shfl_xor(m, o), z2 = __shfl_xor(z, o);
        float mn = fmaxf(m, m2);
        z = z * __expf(m - mn) + z2 * __expf(m2 - mn);
        m = mn;
    }
    if (lane == 0) { rm[wid] = m; rz[wid] = z; }
    __syncthreads();
    m = rm[0]; z = rz[0];
#pragma unroll
    for (int w = 1; w < 4; ++w) {
        float m2 = rm[w], z2 = rz[w];
        float mn = fmaxf(m, m2);
        z = z * __expf(m - mn) + z2 * __expf(m2 - mn);
        m = mn;
    }
    float scale = (1.0f - pc[r]) / z;
    float4* row = (float4*)(out + (size_t)r * OUTW);
    for (int i = tid; i < VV / 4; i += 256) {
        float4 l = row[i];
        l.x = __expf(l.x - m) * scale;
        l.y = __expf(l.y - m) * scale;
        l.z = __expf(l.z - m) * scale;
        l.w = __expf(l.w - m) * scale;
        row[i] = l;
    }
}

// ---------------------------------------------------------------- launcher
extern "C" void kernel_launch(void* const* d_in, const int* in_sizes, int n_in,
                              void* d_out, int out_size, void* d_ws, size_t ws_size,
                              hipStream_t stream) {
    (void)in_sizes; (void)n_in; (void)out_size;
    const float* query = (const float*)d_in[0];
    const float* mem   = (const float*)d_in[1];
    const int*   mask  = (const int*)d_in[2];
    const float* smap  = (const float*)d_in[3];
    const float* Win   = (const float*)d_in[4];
    const float* Wc    = (const float*)d_in[5];
    const float* bc    = (const float*)d_in[6];
    const float* Wg    = (const float*)d_in[7];
    const float* bg    = (const float*)d_in[8];
    float* out = (float*)d_out;

    // fixed ws region (~8 MB), then a reusable 'rest' region
    char* w = (char*)d_ws;
    float* pc   = (float*)w;                                  // 2048
    int*   sidx = (int*)(w + 8192);                           // 2048
    float* pm   = (float*)(w + 16384);                        // 2048*256
    float* pz   = pm + (size_t)2048 * 256;
    unsigned short* Qb = (unsigned short*)(pz + (size_t)2048 * 256);
    char* rest = (char*)(Qb + (size_t)BT * DD);
    size_t rest_sz = ws_size - (size_t)(rest - w);
    float* QW   = (float*)rest;                               // 8 MB (copy phase)
    float* attn = QW + (size_t)BT * DD;                       // 4 MB (copy phase)
    unsigned short* Wt = (unsigned short*)rest;               // gen phase (aliased)

    k_srcidx<<<512, 256, 0, stream>>>(smap, sidx);
    k_pcopy <<<512, 256, 0, stream>>>(query, Wc, bc, pc);
    k_convert_q<<<2048, 256, 0, stream>>>(query, Qb);

    k_gemm_f32<0><<<dim3(16, 32, 1), 256, 0, stream>>>(
        query, DD, 0LL, Win, DD, 0LL, QW, DD, 0LL, DD);
    k_gemm_f32<1><<<dim3(8, 8, 4), 256, 0, stream>>>(
        QW, DD, (long long)SS * DD, mem, DD, (long long)SS * DD,
        attn, SS, (long long)SS * SS, DD);
    k_copy_softmax<<<BT, 256, 0, stream>>>(attn, mask, pc, sidx, out);

    // gen path, chunked over n-panels to fit ws (panel = 128 cols, 256 KB bf16)
    long maxp = (long)(rest_sz / ((size_t)128 * DD * 2));
    if (maxp > 250) maxp = 250;
    if (maxp < 1) maxp = 1;
    for (int p0 = 0; p0 < 250; p0 += (int)maxp) {
        int np = (int)((250 - p0 < maxp) ? (250 - p0) : maxp);
        k_transpose_w<<<dim3(np * 2, 16), 256, 0, stream>>>(Wg, Wt, p0 * 128);
        k_gen_logits<<<16 * np, 256, 0, stream>>>(Qb, Wt, p0, bg, out, pm, pz);
    }
    k_gen_softmax<<<BT, 256, 0, stream>>>(out, pm, pz, pc);
}